// Round 15
// baseline (120.611 us; speedup 1.0000x reference)
//
#include <hip/hip_runtime.h>

#define L_LEN  1024
#define FDIM   16
#define PERIOD 24
#define HDIM   128
#define BATCH  1024
#define DDIM   (L_LEN*FDIM)      // 16384
#define NH3    (3*HDIM)          // 384
#define THALF  12
#define NCLS   10
#define FH     (FDIM*HDIM)       // 2048
#define NLB    8                 // l-strip per build_wp block
#define PCHUNK 4                 // phase_sums l-chunks

typedef short bf16x8  __attribute__((ext_vector_type(8)));
typedef short bf16x16 __attribute__((ext_vector_type(16)));
typedef float f32x4   __attribute__((ext_vector_type(4)));
typedef unsigned int u32x4 __attribute__((ext_vector_type(4)));

__device__ __forceinline__ unsigned short f2bf(float f) {
    unsigned int u = __float_as_uint(f);
    u += 0x7FFFu + ((u >> 16) & 1u);           // RNE
    return (unsigned short)(u >> 16);
}
__device__ __forceinline__ float cinv(int p) { return (p < 16) ? (1.0f/43.0f) : (1.0f/42.0f); }

// ---------------- kernel B1: partial per-phase column sums (4 l-chunks, 384 blocks) ----------------
__global__ void phase_sums_part(const float* __restrict__ We1, const float* __restrict__ We2,
                                float* __restrict__ u4) {
    int idx = blockIdx.x * blockDim.x + threadIdx.x;
    if (idx >= 2 * PERIOD * (FH / 4) * PCHUNK) return;
    int c    = idx / (2 * PERIOD * (FH / 4));
    int rem  = idx % (2 * PERIOD * (FH / 4));
    int w    = rem / (PERIOD * (FH / 4));
    int rem2 = rem % (PERIOD * (FH / 4));
    int p    = rem2 / (FH / 4);
    int fh4  = rem2 % (FH / 4);
    const float* W = w ? We2 : We1;
    int lbeg = c * (L_LEN / PCHUNK);
    int lend = lbeg + (L_LEN / PCHUNK);
    int l0   = lbeg + ((p - lbeg) % PERIOD + PERIOD) % PERIOD;
    f32x4 s = {0.f, 0.f, 0.f, 0.f};
    for (int l = l0; l < lend; l += PERIOD)
        s += *(const f32x4*)&W[(size_t)l * FH + fh4 * 4];
    *(f32x4*)&u4[(size_t)c * (2 * PERIOD * FH) + (size_t)w * PERIOD * FH + p * FH + fh4 * 4] = s;
}

// ---------------- kernel B2: u = sum of 4 partials ----------------
__global__ void phase_reduce(const float* __restrict__ u4, float* __restrict__ u) {
    int idx = blockIdx.x * blockDim.x + threadIdx.x;
    if (idx >= 2 * PERIOD * (FH / 4)) return;
    size_t o = (size_t)idx * 4;
    f32x4 s = *(const f32x4*)&u4[o];
    #pragma unroll
    for (int c = 1; c < PCHUNK; ++c)
        s += *(const f32x4*)&u4[(size_t)c * (2 * PERIOD * FH) + o];
    *(f32x4*)&u[o] = s;
}

// ---------------- kernel C: build W' (bf16) — register-window, spill-free ----------------
__launch_bounds__(256, 3)
__global__ void build_wp(const float* __restrict__ We0, const float* __restrict__ We2,
                         const float* __restrict__ u, unsigned short* __restrict__ Wp) {
    __shared__ unsigned short tile[3][NLB][16][18];   // 13.8 KB
    int f  = threadIdx.x >> 4;
    int hl = threadIdx.x & 15;
    int h  = blockIdx.x * 16 + hl;
    int l0 = blockIdx.y * NLB;
    int fh = f * HDIM + h;
    const float* u1 = u;
    const float* u2 = u + PERIOD * FH;

    float w0[NLB + 25], w2[NLB + 25];
    #pragma unroll
    for (int i = 0; i < NLB + 25; ++i) {
        int j = l0 - THALF + i;
        if (j >= 0 && j < L_LEN) {
            w0[i] = We0[(size_t)j * FH + fh];
            w2[i] = We2[(size_t)j * FH + fh];
        } else { w0[i] = 0.f; w2[i] = 0.f; }
    }

    float Sv1 = 0.f, Sv2 = 0.f;
    #pragma unroll
    for (int p = 0; p < PERIOD; ++p) {
        float ci = cinv(p);
        Sv1 += u1[p * FH + fh] * ci;
        Sv2 += u2[p * FH + fh] * ci;
    }

    float s0 = 0.f, s2 = 0.f;
    #pragma unroll
    for (int i = 0; i < 25; ++i) { s0 += w0[i]; s2 += w2[i]; }

    const float inv25 = 1.0f / 25.0f;
    #pragma unroll
    for (int r = 0; r < NLB; ++r) {
        int l = l0 + r;
        float out0 = s0 * inv25;
        float mav1, mav2;
        if (l >= THALF && l < L_LEN - THALF) {
            int pr = (l + THALF) % PERIOD;
            float cr = cinv(pr);
            mav1 = (Sv1 + u1[pr * FH + fh] * cr) * inv25;
            mav2 = (Sv2 + u2[pr * FH + fh] * cr) * inv25;
        } else {
            mav1 = 0.f; mav2 = 0.f;
            #pragma unroll
            for (int dl = -THALF; dl <= THALF; ++dl) {
                int j = l + dl;
                if (j >= 0 && j < L_LEN) {
                    int p = j % PERIOD;
                    float ci = cinv(p);
                    mav1 += u1[p * FH + fh] * ci;
                    mav2 += u2[p * FH + fh] * ci;
                }
            }
            mav1 *= inv25; mav2 *= inv25;
        }
        int   pl  = l % PERIOD;
        float cl  = cinv(pl);
        float v1l = u1[pl * FH + fh] * cl;
        float v2l = u2[pl * FH + fh] * cl;
        float out1 = v1l - mav1;
        float out2 = w2[r + THALF] - s2 * inv25 - v2l + mav2;

        tile[0][r][hl][f] = f2bf(out0);
        tile[1][r][hl][f] = f2bf(out1);
        tile[2][r][hl][f] = f2bf(out2);

        s0 += w0[r + 25] - w0[r];
        s2 += w2[r + 25] - w2[r];
    }
    __syncthreads();

    {
        int cid = threadIdx.x;
        #pragma unroll
        for (int pass = 0; pass < 2; ++pass, cid += 256) {
            if (cid < 3 * 16 * NLB) {
                int m  = cid / (16 * NLB);
                int rm = cid % (16 * NLB);
                int h2 = rm / NLB;
                int ll = rm % NLB;
                const unsigned int* src = (const unsigned int*)&tile[m][ll][h2][0];
                union { unsigned int d[8]; bf16x16 v; } cvt;
                #pragma unroll
                for (int i = 0; i < 8; ++i) cvt.d[i] = src[i];
                *(bf16x16*)&Wp[(size_t)(m * HDIM + blockIdx.x * 16 + h2) * DDIM
                               + (size_t)(l0 + ll) * FDIM] = cvt.v;
            }
        }
    }
}

// ---------------- kernel D: part[z] = x @ Wp^T — A direct-to-reg (no A LDS), B DMA dbuf ----------------
#define GBM 64
#define GBN 128
#define GBK 64
#define GSPLIT 16
#define GKSPL (DDIM / GSPLIT)    // 1024
#define GKST  (GKSPL / GBK)      // 16
#define NWG   (16 * 3 * GSPLIT)  // 768 blocks, %8==0 (bijective XCD swizzle)

__launch_bounds__(256, 3)
__global__ void gemm5(const float* __restrict__ x, const unsigned short* __restrict__ Wp,
                      float* __restrict__ part) {
    __shared__ unsigned short Bs[2][GBN * GBK];   // 2 x 16 KB only
    int bid = blockIdx.x;
    int swz = (bid & 7) * (NWG / 8) + (bid >> 3);
    int bz  = swz / 48;
    int rem = swz % 48;
    int by  = rem / 16;
    int bx  = rem % 16;
    int m0 = bx * GBM, n0 = by * GBN, k0 = bz * GKSPL;
    int tid = threadIdx.x, lane = tid & 63, wave = tid >> 6;
    int wm = wave >> 1, wn = wave & 1;
    int frow = lane & 15, hi4 = lane >> 4;

    // A direct: lane covers rows (m0+wm*32+i*16+frow), k = k0 + s*64 + ks*32 + hi4*8
    const float* ar = x + (size_t)(m0 + wm * 32 + frow) * DDIM + k0 + hi4 * 8;
    int brc  = lane >> 3;                       // B staging: row within 8-row chunk
    int bsg  = (lane & 7) ^ brc;                // T2 source-pre-swizzle

    f32x4 Ra[8], Rb[8];                         // raw A for one step: (i,ks) x 2 f32x4
    f32x4 acc[2][4] = {};

    auto aload = [&](f32x4* R, int s) {
        if (s >= GKST) s = 0;                   // clamped dummy (kept in-bounds)
        #pragma unroll
        for (int i = 0; i < 2; ++i)
            #pragma unroll
            for (int ks = 0; ks < 2; ++ks) {
                const float* p = ar + (size_t)i * 16 * DDIM + s * GBK + ks * 32;
                R[(i * 2 + ks) * 2]     = *(const f32x4*)p;
                R[(i * 2 + ks) * 2 + 1] = *(const f32x4*)(p + 4);
            }
    };
    auto bstage = [&](int buf, int s) {
        #pragma unroll
        for (int q = 0; q < 4; ++q) {
            int c = wave * 4 + q;               // 8-row chunk id (0..15)
            const unsigned short* g = Wp + (size_t)(n0 + c * 8 + brc) * DDIM
                                        + k0 + s * GBK + bsg * 8;
            __builtin_amdgcn_global_load_lds(
                (const __attribute__((address_space(1))) void*)g,
                (__attribute__((address_space(3))) void*)&Bs[buf][c * 512], 16, 0, 0);
        }
    };
    // cvt raw -> 4 bf16 fragments (frees the raw regs for the next aload)
    auto cvtfrag = [&](const f32x4* R, bf16x8* fa) {
        #pragma unroll
        for (int q = 0; q < 4; ++q) {
            union { unsigned int d[4]; bf16x8 v; } af;
            const f32x4 lo = R[q * 2], hi = R[q * 2 + 1];
            asm("v_cvt_pk_bf16_f32 %0, %1, %2" : "=v"(af.d[0]) : "v"(lo[0]), "v"(lo[1]));
            asm("v_cvt_pk_bf16_f32 %0, %1, %2" : "=v"(af.d[1]) : "v"(lo[2]), "v"(lo[3]));
            asm("v_cvt_pk_bf16_f32 %0, %1, %2" : "=v"(af.d[2]) : "v"(hi[0]), "v"(hi[1]));
            asm("v_cvt_pk_bf16_f32 %0, %1, %2" : "=v"(af.d[3]) : "v"(hi[2]), "v"(hi[3]));
            fa[q] = af.v;                       // q = i*2 + ks
        }
    };
    auto mfmas = [&](int buf, const bf16x8* fa) {
        #pragma unroll
        for (int ks = 0; ks < 2; ++ks) {
            bf16x8 bv[4];
            #pragma unroll
            for (int j = 0; j < 4; ++j) {
                int rB = wn * 64 + j * 16 + frow;
                int sL = (ks * 4 + hi4) ^ (frow & 7);    // un-swizzle on read
                bv[j] = *(const bf16x8*)&Bs[buf][rB * GBK + sL * 8];
            }
            #pragma unroll
            for (int i = 0; i < 2; ++i)
                #pragma unroll
                for (int j = 0; j < 4; ++j)
                    acc[i][j] = __builtin_amdgcn_mfma_f32_16x16x32_bf16(fa[i * 2 + ks], bv[j], acc[i][j], 0, 0, 0);
        }
    };

    // prologue: A(0),A(1) to regs; B(0) DMA; barrier drains B0
    aload(Ra, 0);
    aload(Rb, 1);
    bstage(0, 0);
    __syncthreads();

    for (int s2 = 0; s2 < GKST; s2 += 2) {
        {   int s = s2;                                  // even: compute from Ra, B buf 0
            bf16x8 fa[4];
            cvtfrag(Ra, fa);                             // Ra free after this
            if (s + 1 < GKST) bstage(1, s + 1);
            aload(Ra, s + 2);                            // 2 steps of latency cover
            mfmas(0, fa);
            __syncthreads();                             // drains B(s+1) DMA (+A, already covered)
        }
        {   int s = s2 + 1;                              // odd: compute from Rb, B buf 1
            bf16x8 fa[4];
            cvtfrag(Rb, fa);
            if (s + 1 < GKST) {
                bstage(0, s + 1);
                aload(Rb, s + 2);
                mfmas(1, fa);
                __syncthreads();
            } else {
                mfmas(1, fa);                            // final step
            }
        }
    }

    // epilogue: plain streaming stores to this k-split's private slab
    float* pslab = part + (size_t)bz * (BATCH * NH3);
    int orow = (lane >> 4) * 4, ocol = lane & 15;   // C/D: col=lane&15, row=(lane>>4)*4+r
    #pragma unroll
    for (int i = 0; i < 2; ++i)
        #pragma unroll
        for (int j = 0; j < 4; ++j)
            #pragma unroll
            for (int r = 0; r < 4; ++r)
                pslab[(size_t)(m0 + wm*32 + i*16 + orow + r) * NH3
                      + (n0 + wn*64 + j*16 + ocol)] = acc[i][j][r];
}

// ---------------- kernel E: fused MLP tail — one block per batch row ----------------
__launch_bounds__(512, 4)
__global__ void mlp_fused(const float* __restrict__ part, const float* __restrict__ be0,
                          const float* __restrict__ be1, const float* __restrict__ be2,
                          const float* __restrict__ Wf1, const float* __restrict__ bf1,
                          const float* __restrict__ Wf2, const float* __restrict__ bf2,
                          float* __restrict__ out) {
    __shared__ float fr[NH3];
    __shared__ float hp[4][HDIM];
    __shared__ float hs[HDIM];
    int b = blockIdx.x, tid = threadIdx.x;

    if (tid < NH3) {
        float v = (tid < HDIM) ? be0[tid]
                : (tid < 2*HDIM ? be1[tid - HDIM] : be2[tid - 2*HDIM]);
        #pragma unroll
        for (int z = 0; z < GSPLIT; ++z)
            v += part[(size_t)z * (BATCH * NH3) + (size_t)b * NH3 + tid];
        fr[tid] = v;
    }
    __syncthreads();

    int j = tid & 127, c = tid >> 7;
    int i0 = c * 96;
    float p0 = 0.f, p1 = 0.f, p2 = 0.f, p3 = 0.f;
    #pragma unroll
    for (int k = 0; k < 24; ++k) {
        p0 = fmaf(fr[i0 + k],      Wf1[(size_t)(i0 + k)      * HDIM + j], p0);
        p1 = fmaf(fr[i0 + 24 + k], Wf1[(size_t)(i0 + 24 + k) * HDIM + j], p1);
        p2 = fmaf(fr[i0 + 48 + k], Wf1[(size_t)(i0 + 48 + k) * HDIM + j], p2);
        p3 = fmaf(fr[i0 + 72 + k], Wf1[(size_t)(i0 + 72 + k) * HDIM + j], p3);
    }
    hp[c][j] = (p0 + p1) + (p2 + p3);
    __syncthreads();

    if (tid < HDIM) {
        float v = bf1[tid] + ((hp[0][tid] + hp[1][tid]) + (hp[2][tid] + hp[3][tid]));
        hs[tid] = fmaxf(v, 0.f);
    }
    __syncthreads();

    int lane = tid & 63, wave = tid >> 6;
    for (int cc = wave; cc < NCLS; cc += 8) {
        float pp = hs[lane] * Wf2[(size_t)lane * NCLS + cc];
        pp = fmaf(hs[lane + 64], Wf2[(size_t)(lane + 64) * NCLS + cc], pp);
        #pragma unroll
        for (int off = 32; off; off >>= 1) pp += __shfl_down(pp, off);
        if (lane == 0) out[(size_t)b * NCLS + cc] = pp + bf2[cc];
    }
}

extern "C" void kernel_launch(void* const* d_in, const int* in_sizes, int n_in,
                              void* d_out, int out_size, void* d_ws, size_t ws_size,
                              hipStream_t stream) {
    const float* x   = (const float*)d_in[0];
    const float* We0 = (const float*)d_in[1];
    const float* be0 = (const float*)d_in[2];
    const float* We1 = (const float*)d_in[3];
    const float* be1 = (const float*)d_in[4];
    const float* We2 = (const float*)d_in[5];
    const float* be2 = (const float*)d_in[6];
    const float* Wf1 = (const float*)d_in[7];
    const float* bf1 = (const float*)d_in[8];
    const float* Wf2 = (const float*)d_in[9];
    const float* bf2 = (const float*)d_in[10];
    float* out = (float*)d_out;

    char* wsb = (char*)d_ws;
    size_t off = 0;
    unsigned short* Wp = (unsigned short*)(wsb + off); off += (size_t)NH3 * DDIM * sizeof(unsigned short);   // 12.6 MB
    float* u    = (float*)(wsb + off); off += (size_t)2 * PERIOD * FH * sizeof(float);                       // 0.39 MB
    float* u4   = (float*)(wsb + off); off += (size_t)PCHUNK * 2 * PERIOD * FH * sizeof(float);              // 1.57 MB
    float* part = (float*)(wsb + off); off += (size_t)GSPLIT * BATCH * NH3 * sizeof(float);                  // 25.2 MB

    phase_sums_part<<<(2 * PERIOD * (FH / 4) * PCHUNK + 255) / 256, 256, 0, stream>>>(We1, We2, u4);
    phase_reduce<<<(2 * PERIOD * (FH / 4) + 255) / 256, 256, 0, stream>>>(u4, u);
    build_wp<<<dim3(8, L_LEN / NLB), 256, 0, stream>>>(We0, We2, u, Wp);
    gemm5<<<NWG, 256, 0, stream>>>(x, Wp, part);
    mlp_fused<<<BATCH, 512, 0, stream>>>(part, be0, be1, be2, Wf1, bf1, Wf2, bf2, out);
}

// Round 16
// 81.335 us; speedup vs baseline: 1.4829x; 1.4829x over previous
//
#include <hip/hip_runtime.h>

#define L_LEN  1024
#define FDIM   16
#define PERIOD 24
#define HDIM   128
#define BATCH  1024
#define DDIM   (L_LEN*FDIM)      // 16384
#define NH3    (3*HDIM)          // 384
#define THALF  12
#define NCLS   10
#define FH     (FDIM*HDIM)       // 2048
#define NLB    8                 // l-strip per build_wp block
#define PCHUNK 4                 // phase_sums l-chunks

typedef short bf16x8  __attribute__((ext_vector_type(8)));
typedef short bf16x16 __attribute__((ext_vector_type(16)));
typedef float f32x4   __attribute__((ext_vector_type(4)));
typedef unsigned int u32x4 __attribute__((ext_vector_type(4)));

__device__ __forceinline__ unsigned short f2bf(float f) {
    unsigned int u = __float_as_uint(f);
    u += 0x7FFFu + ((u >> 16) & 1u);           // RNE
    return (unsigned short)(u >> 16);
}
__device__ __forceinline__ float cinv(int p) { return (p < 16) ? (1.0f/43.0f) : (1.0f/42.0f); }

// ---------------- kernel B1: partial per-phase column sums (4 l-chunks, 384 blocks) ----------------
__global__ void phase_sums_part(const float* __restrict__ We1, const float* __restrict__ We2,
                                float* __restrict__ u4) {
    int idx = blockIdx.x * blockDim.x + threadIdx.x;
    if (idx >= 2 * PERIOD * (FH / 4) * PCHUNK) return;
    int c    = idx / (2 * PERIOD * (FH / 4));
    int rem  = idx % (2 * PERIOD * (FH / 4));
    int w    = rem / (PERIOD * (FH / 4));
    int rem2 = rem % (PERIOD * (FH / 4));
    int p    = rem2 / (FH / 4);
    int fh4  = rem2 % (FH / 4);
    const float* W = w ? We2 : We1;
    int lbeg = c * (L_LEN / PCHUNK);
    int lend = lbeg + (L_LEN / PCHUNK);
    int l0   = lbeg + ((p - lbeg) % PERIOD + PERIOD) % PERIOD;
    f32x4 s = {0.f, 0.f, 0.f, 0.f};
    for (int l = l0; l < lend; l += PERIOD)
        s += *(const f32x4*)&W[(size_t)l * FH + fh4 * 4];
    *(f32x4*)&u4[(size_t)c * (2 * PERIOD * FH) + (size_t)w * PERIOD * FH + p * FH + fh4 * 4] = s;
}

// ---------------- kernel B2: u = sum of 4 partials ----------------
__global__ void phase_reduce(const float* __restrict__ u4, float* __restrict__ u) {
    int idx = blockIdx.x * blockDim.x + threadIdx.x;
    if (idx >= 2 * PERIOD * (FH / 4)) return;
    size_t o = (size_t)idx * 4;
    f32x4 s = *(const f32x4*)&u4[o];
    #pragma unroll
    for (int c = 1; c < PCHUNK; ++c)
        s += *(const f32x4*)&u4[(size_t)c * (2 * PERIOD * FH) + o];
    *(f32x4*)&u[o] = s;
}

// ---------------- kernel C: build W' (bf16) — register-window, spill-free ----------------
__launch_bounds__(256, 3)
__global__ void build_wp(const float* __restrict__ We0, const float* __restrict__ We2,
                         const float* __restrict__ u, unsigned short* __restrict__ Wp) {
    __shared__ unsigned short tile[3][NLB][16][18];   // 13.8 KB
    int f  = threadIdx.x >> 4;
    int hl = threadIdx.x & 15;
    int h  = blockIdx.x * 16 + hl;
    int l0 = blockIdx.y * NLB;
    int fh = f * HDIM + h;
    const float* u1 = u;
    const float* u2 = u + PERIOD * FH;

    float w0[NLB + 25], w2[NLB + 25];
    #pragma unroll
    for (int i = 0; i < NLB + 25; ++i) {
        int j = l0 - THALF + i;
        if (j >= 0 && j < L_LEN) {
            w0[i] = We0[(size_t)j * FH + fh];
            w2[i] = We2[(size_t)j * FH + fh];
        } else { w0[i] = 0.f; w2[i] = 0.f; }
    }

    float Sv1 = 0.f, Sv2 = 0.f;
    #pragma unroll
    for (int p = 0; p < PERIOD; ++p) {
        float ci = cinv(p);
        Sv1 += u1[p * FH + fh] * ci;
        Sv2 += u2[p * FH + fh] * ci;
    }

    float s0 = 0.f, s2 = 0.f;
    #pragma unroll
    for (int i = 0; i < 25; ++i) { s0 += w0[i]; s2 += w2[i]; }

    const float inv25 = 1.0f / 25.0f;
    #pragma unroll
    for (int r = 0; r < NLB; ++r) {
        int l = l0 + r;
        float out0 = s0 * inv25;
        float mav1, mav2;
        if (l >= THALF && l < L_LEN - THALF) {
            int pr = (l + THALF) % PERIOD;
            float cr = cinv(pr);
            mav1 = (Sv1 + u1[pr * FH + fh] * cr) * inv25;
            mav2 = (Sv2 + u2[pr * FH + fh] * cr) * inv25;
        } else {
            mav1 = 0.f; mav2 = 0.f;
            #pragma unroll
            for (int dl = -THALF; dl <= THALF; ++dl) {
                int j = l + dl;
                if (j >= 0 && j < L_LEN) {
                    int p = j % PERIOD;
                    float ci = cinv(p);
                    mav1 += u1[p * FH + fh] * ci;
                    mav2 += u2[p * FH + fh] * ci;
                }
            }
            mav1 *= inv25; mav2 *= inv25;
        }
        int   pl  = l % PERIOD;
        float cl  = cinv(pl);
        float v1l = u1[pl * FH + fh] * cl;
        float v2l = u2[pl * FH + fh] * cl;
        float out1 = v1l - mav1;
        float out2 = w2[r + THALF] - s2 * inv25 - v2l + mav2;

        tile[0][r][hl][f] = f2bf(out0);
        tile[1][r][hl][f] = f2bf(out1);
        tile[2][r][hl][f] = f2bf(out2);

        s0 += w0[r + 25] - w0[r];
        s2 += w2[r + 25] - w2[r];
    }
    __syncthreads();

    {
        int cid = threadIdx.x;
        #pragma unroll
        for (int pass = 0; pass < 2; ++pass, cid += 256) {
            if (cid < 3 * 16 * NLB) {
                int m  = cid / (16 * NLB);
                int rm = cid % (16 * NLB);
                int h2 = rm / NLB;
                int ll = rm % NLB;
                const unsigned int* src = (const unsigned int*)&tile[m][ll][h2][0];
                union { unsigned int d[8]; bf16x16 v; } cvt;
                #pragma unroll
                for (int i = 0; i < 8; ++i) cvt.d[i] = src[i];
                *(bf16x16*)&Wp[(size_t)(m * HDIM + blockIdx.x * 16 + h2) * DDIM
                               + (size_t)(l0 + ll) * FDIM] = cvt.v;
            }
        }
    }
}

// ---------------- kernel D: part[z] = x @ Wp^T — R14 champion (reg-A + LDS, B DMA, stores) ----------------
#define GBM 64
#define GBN 128
#define GBK 64
#define GSPLIT 16
#define GKSPL (DDIM / GSPLIT)    // 1024
#define GKST  (GKSPL / GBK)      // 16
#define LDA   72                 // A LDS stride: 144B ≡ 4 dwords mod 32 -> 2-way (free)
#define NWG   (16 * 3 * GSPLIT)  // 768 blocks, %8==0 (bijective XCD swizzle)

__launch_bounds__(256, 3)
__global__ void gemm2(const float* __restrict__ x, const unsigned short* __restrict__ Wp,
                      float* __restrict__ part) {
    __shared__ unsigned short As[2][GBM * LDA];   // 2 x 9.2 KB
    __shared__ unsigned short Bs[2][GBN * GBK];   // 2 x 16 KB, linear dest, swizzled content
    int bid = blockIdx.x;
    int swz = (bid & 7) * (NWG / 8) + (bid >> 3);
    int bz  = swz / 48;
    int rem = swz % 48;
    int by  = rem / 16;
    int bx  = rem % 16;
    int m0 = bx * GBM, n0 = by * GBN, k0 = bz * GKSPL;
    int tid = threadIdx.x, lane = tid & 63, wave = tid >> 6;
    int wm = wave >> 1, wn = wave & 1;

    int arow = tid >> 2, aseg = tid & 3;
    const float* ag = x + (size_t)(m0 + arow) * DDIM + k0 + aseg * 16;
    int brc  = lane >> 3;                       // row within 8-row chunk
    int bsg  = (lane & 7) ^ brc;                // T2 source-pre-swizzle

    f32x4 Ra[4], Rb[4];
    f32x4 acc[2][4] = {};

    auto aload = [&](f32x4* R, int s) {
        const float* a = ag + s * GBK;
        #pragma unroll
        for (int i = 0; i < 4; ++i) R[i] = *(const f32x4*)(a + 4 * i);
    };
    auto astore = [&](const f32x4* R, int buf) {
        unsigned int w[8];
        #pragma unroll
        for (int t = 0; t < 8; ++t) {
            float lo = R[t >> 1][(t & 1) * 2];
            float hi = R[t >> 1][(t & 1) * 2 + 1];
            asm("v_cvt_pk_bf16_f32 %0, %1, %2" : "=v"(w[t]) : "v"(lo), "v"(hi));
        }
        unsigned short* dst = &As[buf][arow * LDA + aseg * 16];
        u32x4 v0 = {w[0], w[1], w[2], w[3]};
        u32x4 v1 = {w[4], w[5], w[6], w[7]};
        *(u32x4*)dst       = v0;
        *(u32x4*)(dst + 8) = v1;
    };
    auto bstage = [&](int buf, int s) {
        #pragma unroll
        for (int q = 0; q < 4; ++q) {
            int c = wave * 4 + q;                  // 8-row chunk id (0..15)
            const unsigned short* g = Wp + (size_t)(n0 + c * 8 + brc) * DDIM
                                        + k0 + s * GBK + bsg * 8;
            __builtin_amdgcn_global_load_lds(
                (const __attribute__((address_space(1))) void*)g,
                (__attribute__((address_space(3))) void*)&Bs[buf][c * 512], 16, 0, 0);
        }
    };
    int frow = lane & 15, hi4 = lane >> 4;
    auto compute = [&](int buf) {
        #pragma unroll
        for (int ks = 0; ks < 2; ++ks) {
            bf16x8 av[2], bv[4];
            #pragma unroll
            for (int i = 0; i < 2; ++i)
                av[i] = *(const bf16x8*)&As[buf][(wm*32 + i*16 + frow) * LDA + ks*32 + hi4*8];
            #pragma unroll
            for (int j = 0; j < 4; ++j) {
                int rB = wn*64 + j*16 + frow;
                int sL = (ks*4 + hi4) ^ (frow & 7);    // un-swizzle on read
                bv[j] = *(const bf16x8*)&Bs[buf][rB * GBK + sL * 8];
            }
            #pragma unroll
            for (int i = 0; i < 2; ++i)
                #pragma unroll
                for (int j = 0; j < 4; ++j)
                    acc[i][j] = __builtin_amdgcn_mfma_f32_16x16x32_bf16(av[i], bv[j], acc[i][j], 0, 0, 0);
        }
    };

    // prologue: regs k0,k1; B0 DMA; A0 in LDS; barrier drains all
    aload(Ra, 0); aload(Rb, 1); bstage(0, 0); astore(Ra, 0);
    __syncthreads();

    for (int s2 = 0; s2 < GKST; s2 += 2) {
        {   int s = s2;                                  // even step, bufs 0
            if (s + 1 < GKST) bstage(1, s + 1);
            if (s + 2 < GKST) aload(Ra, s + 2);
            if (s + 1 < GKST) astore(Rb, 1);
            compute(0);
            __syncthreads();
        }
        {   int s = s2 + 1;                              // odd step, bufs 1
            if (s + 1 < GKST) bstage(0, s + 1);
            if (s + 2 < GKST) aload(Rb, s + 2);
            if (s + 1 < GKST) astore(Ra, 0);
            compute(1);
            __syncthreads();
        }
    }

    // epilogue: plain streaming stores to this k-split's private slab (no atomics)
    float* pslab = part + (size_t)bz * (BATCH * NH3);
    int orow = (lane >> 4) * 4, ocol = lane & 15;   // C/D: col=lane&15, row=(lane>>4)*4+r
    #pragma unroll
    for (int i = 0; i < 2; ++i)
        #pragma unroll
        for (int j = 0; j < 4; ++j)
            #pragma unroll
            for (int r = 0; r < 4; ++r)
                pslab[(size_t)(m0 + wm*32 + i*16 + orow + r) * NH3
                      + (n0 + wn*64 + j*16 + ocol)] = acc[i][j][r];
}

// ---------------- kernel E: fused MLP tail — 4 batch rows per block, shared Wf1 loads ----------------
// Each Wf1[i][j] load feeds 4 row-accumulators (Wf1 traffic 201 MB -> 50 MB).
__launch_bounds__(1024, 2)
__global__ void mlp_fused2(const float* __restrict__ part, const float* __restrict__ be0,
                           const float* __restrict__ be1, const float* __restrict__ be2,
                           const float* __restrict__ Wf1, const float* __restrict__ bf1,
                           const float* __restrict__ Wf2, const float* __restrict__ bf2,
                           float* __restrict__ out) {
    __shared__ float fr[4][NH3];        // 6 KB
    __shared__ float hp[8][4][HDIM];    // 16 KB
    __shared__ float hs[4][HDIM];       // 2 KB
    int b0 = blockIdx.x * 4, tid = threadIdx.x;

    for (int e = tid; e < 4 * NH3; e += 1024) {       // slab-reduce 4 rows
        int rr = e / NH3, cc = e % NH3;
        float v = (cc < HDIM) ? be0[cc]
                : (cc < 2*HDIM ? be1[cc - HDIM] : be2[cc - 2*HDIM]);
        #pragma unroll
        for (int z = 0; z < GSPLIT; ++z)              // 16 independent loads
            v += part[(size_t)z * (BATCH * NH3) + (size_t)(b0 + rr) * NH3 + cc];
        fr[rr][cc] = v;
    }
    __syncthreads();

    int j = tid & 127, c = tid >> 7;                  // c = 0..7, 48 i's each
    int i0 = c * 48;
    float a0 = 0.f, a1 = 0.f, a2 = 0.f, a3 = 0.f;     // 4 independent chains of 48
    #pragma unroll
    for (int k = 0; k < 48; ++k) {
        float w = Wf1[(size_t)(i0 + k) * HDIM + j];   // ONE load, FOUR fmas
        float f0 = fr[0][i0 + k], f1 = fr[1][i0 + k];
        float f2 = fr[2][i0 + k], f3 = fr[3][i0 + k];
        a0 = fmaf(f0, w, a0);
        a1 = fmaf(f1, w, a1);
        a2 = fmaf(f2, w, a2);
        a3 = fmaf(f3, w, a3);
    }
    hp[c][0][j] = a0; hp[c][1][j] = a1; hp[c][2][j] = a2; hp[c][3][j] = a3;
    __syncthreads();

    if (tid < 4 * HDIM) {
        int rr = tid >> 7, jj = tid & 127;
        float v = bf1[jj];
        #pragma unroll
        for (int cc = 0; cc < 8; ++cc) v += hp[cc][rr][jj];
        hs[rr][jj] = fmaxf(v, 0.f);
    }
    __syncthreads();

    int lane = tid & 63, wave = tid >> 6;             // 16 waves
    int rr = wave & 3, base = wave >> 2;              // wave -> (row, class-stride-4 set)
    #pragma unroll
    for (int cc = base; cc < NCLS; cc += 4) {
        float pp = hs[rr][lane] * Wf2[(size_t)lane * NCLS + cc];
        pp = fmaf(hs[rr][lane + 64], Wf2[(size_t)(lane + 64) * NCLS + cc], pp);
        #pragma unroll
        for (int off = 32; off; off >>= 1) pp += __shfl_down(pp, off);
        if (lane == 0) out[(size_t)(b0 + rr) * NCLS + cc] = pp + bf2[cc];
    }
}

extern "C" void kernel_launch(void* const* d_in, const int* in_sizes, int n_in,
                              void* d_out, int out_size, void* d_ws, size_t ws_size,
                              hipStream_t stream) {
    const float* x   = (const float*)d_in[0];
    const float* We0 = (const float*)d_in[1];
    const float* be0 = (const float*)d_in[2];
    const float* We1 = (const float*)d_in[3];
    const float* be1 = (const float*)d_in[4];
    const float* We2 = (const float*)d_in[5];
    const float* be2 = (const float*)d_in[6];
    const float* Wf1 = (const float*)d_in[7];
    const float* bf1 = (const float*)d_in[8];
    const float* Wf2 = (const float*)d_in[9];
    const float* bf2 = (const float*)d_in[10];
    float* out = (float*)d_out;

    char* wsb = (char*)d_ws;
    size_t off = 0;
    unsigned short* Wp = (unsigned short*)(wsb + off); off += (size_t)NH3 * DDIM * sizeof(unsigned short);   // 12.6 MB
    float* u    = (float*)(wsb + off); off += (size_t)2 * PERIOD * FH * sizeof(float);                       // 0.39 MB
    float* u4   = (float*)(wsb + off); off += (size_t)PCHUNK * 2 * PERIOD * FH * sizeof(float);              // 1.57 MB
    float* part = (float*)(wsb + off); off += (size_t)GSPLIT * BATCH * NH3 * sizeof(float);                  // 25.2 MB

    phase_sums_part<<<(2 * PERIOD * (FH / 4) * PCHUNK + 255) / 256, 256, 0, stream>>>(We1, We2, u4);
    phase_reduce<<<(2 * PERIOD * (FH / 4) + 255) / 256, 256, 0, stream>>>(u4, u);
    build_wp<<<dim3(8, L_LEN / NLB), 256, 0, stream>>>(We0, We2, u, Wp);
    gemm2<<<NWG, 256, 0, stream>>>(x, Wp, part);
    mlp_fused2<<<BATCH / 4, 1024, 0, stream>>>(part, be0, be1, be2, Wf1, bf1, Wf2, bf2, out);
}

// Round 17
// 67.548 us; speedup vs baseline: 1.7856x; 1.2041x over previous
//
#include <hip/hip_runtime.h>

#define L_LEN  1024
#define FDIM   16
#define PERIOD 24
#define HDIM   128
#define BATCH  1024
#define DDIM   (L_LEN*FDIM)      // 16384
#define NH3    (3*HDIM)          // 384
#define THALF  12
#define NCLS   10
#define FH     (FDIM*HDIM)       // 2048
#define NLB    8                 // l-strip per build_wp block
#define PCHUNK 4                 // phase_sums l-chunks
#define NSLOT  48                // 24 interior phases + 24 edge l's

typedef short bf16x8  __attribute__((ext_vector_type(8)));
typedef short bf16x16 __attribute__((ext_vector_type(16)));
typedef float f32x4   __attribute__((ext_vector_type(4)));
typedef unsigned int u32x4 __attribute__((ext_vector_type(4)));

__device__ __forceinline__ unsigned short f2bf(float f) {
    unsigned int u = __float_as_uint(f);
    u += 0x7FFFu + ((u >> 16) & 1u);           // RNE
    return (unsigned short)(u >> 16);
}
__device__ __forceinline__ float cinv(int p) { return (p < 16) ? (1.0f/43.0f) : (1.0f/42.0f); }

// ---------------- kernel B1: partial per-phase column sums (4 l-chunks, 384 blocks) ----------------
__global__ void phase_sums_part(const float* __restrict__ We1, const float* __restrict__ We2,
                                float* __restrict__ u4) {
    int idx = blockIdx.x * blockDim.x + threadIdx.x;
    if (idx >= 2 * PERIOD * (FH / 4) * PCHUNK) return;
    int c    = idx / (2 * PERIOD * (FH / 4));
    int rem  = idx % (2 * PERIOD * (FH / 4));
    int w    = rem / (PERIOD * (FH / 4));
    int rem2 = rem % (PERIOD * (FH / 4));
    int p    = rem2 / (FH / 4);
    int fh4  = rem2 % (FH / 4);
    const float* W = w ? We2 : We1;
    int lbeg = c * (L_LEN / PCHUNK);
    int lend = lbeg + (L_LEN / PCHUNK);
    int l0   = lbeg + ((p - lbeg) % PERIOD + PERIOD) % PERIOD;
    f32x4 s = {0.f, 0.f, 0.f, 0.f};
    for (int l = l0; l < lend; l += PERIOD)
        s += *(const f32x4*)&W[(size_t)l * FH + fh4 * 4];
    *(f32x4*)&u4[(size_t)c * (2 * PERIOD * FH) + (size_t)w * PERIOD * FH + p * FH + fh4 * 4] = s;
}

// ---------------- kernel B2: u = sum of 4 partials ----------------
__global__ void phase_reduce(const float* __restrict__ u4, float* __restrict__ u) {
    int idx = blockIdx.x * blockDim.x + threadIdx.x;
    if (idx >= 2 * PERIOD * (FH / 4)) return;
    size_t o = (size_t)idx * 4;
    f32x4 s = *(const f32x4*)&u4[o];
    #pragma unroll
    for (int c = 1; c < PCHUNK; ++c)
        s += *(const f32x4*)&u4[(size_t)c * (2 * PERIOD * FH) + o];
    *(f32x4*)&u[o] = s;
}

// ---------------- kernel B3: u-part tables, periodic in l ----------------
// slot s<24: interior phase p=s:  t1 = v1(p) - (Sv1 + v1c(pr))/25,  t2 = (Sv2 + v2c(pr))/25 - v2(p)
// slot s>=24: edge l (12 low + 12 high): exact clipped moving-average sums.
__global__ void build_tables(const float* __restrict__ u, float* __restrict__ t1,
                             float* __restrict__ t2) {
    int idx = blockIdx.x * blockDim.x + threadIdx.x;   // 48 * 512
    if (idx >= NSLOT * (FH / 4)) return;
    int s   = idx / (FH / 4);
    int fh4 = idx % (FH / 4);
    const float* u1 = u + (size_t)fh4 * 4;
    const float* u2 = u + (size_t)PERIOD * FH + (size_t)fh4 * 4;
    const float inv25 = 1.0f / 25.0f;
    f32x4 v1, v2;
    f32x4 mav1 = {0.f, 0.f, 0.f, 0.f}, mav2 = {0.f, 0.f, 0.f, 0.f};

    if (s < PERIOD) {                                  // interior phase
        int p  = s;
        int pr = (p + THALF) % PERIOD;
        f32x4 Sv1 = {0.f, 0.f, 0.f, 0.f}, Sv2 = {0.f, 0.f, 0.f, 0.f};
        #pragma unroll
        for (int q = 0; q < PERIOD; ++q) {
            float cq = cinv(q);
            Sv1 += *(const f32x4*)&u1[(size_t)q * FH] * cq;
            Sv2 += *(const f32x4*)&u2[(size_t)q * FH] * cq;
        }
        v1 = *(const f32x4*)&u1[(size_t)p * FH] * cinv(p);
        v2 = *(const f32x4*)&u2[(size_t)p * FH] * cinv(p);
        mav1 = (Sv1 + *(const f32x4*)&u1[(size_t)pr * FH] * cinv(pr)) * inv25;
        mav2 = (Sv2 + *(const f32x4*)&u2[(size_t)pr * FH] * cinv(pr)) * inv25;
    } else {                                           // edge l, exact clipped window
        int e = s - PERIOD;
        int l = (e < THALF) ? e : (L_LEN - THALF + (e - THALF));
        int pl = l % PERIOD;
        v1 = *(const f32x4*)&u1[(size_t)pl * FH] * cinv(pl);
        v2 = *(const f32x4*)&u2[(size_t)pl * FH] * cinv(pl);
        #pragma unroll
        for (int dl = -THALF; dl <= THALF; ++dl) {
            int j = l + dl;
            if (j >= 0 && j < L_LEN) {
                int p = j % PERIOD;
                float ci = cinv(p);
                mav1 += *(const f32x4*)&u1[(size_t)p * FH] * ci;
                mav2 += *(const f32x4*)&u2[(size_t)p * FH] * ci;
            }
        }
        mav1 *= inv25; mav2 *= inv25;
    }
    *(f32x4*)&t1[(size_t)s * FH + fh4 * 4] = v1 - mav1;   // out1 = t1
    *(f32x4*)&t2[(size_t)s * FH + fh4 * 4] = mav2 - v2;   // out2 = w2 - s2/25 + t2
}

// ---------------- kernel C: build W' (bf16) — window regs + table lookups ----------------
__launch_bounds__(256, 3)
__global__ void build_wp(const float* __restrict__ We0, const float* __restrict__ We2,
                         const float* __restrict__ t1, const float* __restrict__ t2,
                         unsigned short* __restrict__ Wp) {
    __shared__ unsigned short tile[3][NLB][16][18];   // 13.8 KB
    int f  = threadIdx.x >> 4;
    int hl = threadIdx.x & 15;
    int h  = blockIdx.x * 16 + hl;
    int l0 = blockIdx.y * NLB;
    int fh = f * HDIM + h;

    float w0[NLB + 25], w2[NLB + 25];
    #pragma unroll
    for (int i = 0; i < NLB + 25; ++i) {
        int j = l0 - THALF + i;
        if (j >= 0 && j < L_LEN) {
            w0[i] = We0[(size_t)j * FH + fh];
            w2[i] = We2[(size_t)j * FH + fh];
        } else { w0[i] = 0.f; w2[i] = 0.f; }
    }

    float s0 = 0.f, s2 = 0.f;
    #pragma unroll
    for (int i = 0; i < 25; ++i) { s0 += w0[i]; s2 += w2[i]; }

    const float inv25 = 1.0f / 25.0f;
    #pragma unroll
    for (int r = 0; r < NLB; ++r) {
        int l = l0 + r;
        int slot = (l >= THALF && l < L_LEN - THALF)
                 ? (l % PERIOD)
                 : (PERIOD + ((l < THALF) ? l : (THALF + (l - (L_LEN - THALF)))));
        float tt1 = t1[(size_t)slot * FH + fh];
        float tt2 = t2[(size_t)slot * FH + fh];

        float out0 = s0 * inv25;                        // (T We0)[l]
        float out1 = tt1;                               // S^T We1
        float out2 = w2[r + THALF] - s2 * inv25 + tt2;  // (I-T-S)^T We2

        tile[0][r][hl][f] = f2bf(out0);
        tile[1][r][hl][f] = f2bf(out1);
        tile[2][r][hl][f] = f2bf(out2);

        s0 += w0[r + 25] - w0[r];                       // register-only slide
        s2 += w2[r + 25] - w2[r];
    }
    __syncthreads();

    {
        int cid = threadIdx.x;
        #pragma unroll
        for (int pass = 0; pass < 2; ++pass, cid += 256) {
            if (cid < 3 * 16 * NLB) {
                int m  = cid / (16 * NLB);
                int rm = cid % (16 * NLB);
                int h2 = rm / NLB;
                int ll = rm % NLB;
                const unsigned int* src = (const unsigned int*)&tile[m][ll][h2][0];
                union { unsigned int d[8]; bf16x16 v; } cvt;
                #pragma unroll
                for (int i = 0; i < 8; ++i) cvt.d[i] = src[i];
                *(bf16x16*)&Wp[(size_t)(m * HDIM + blockIdx.x * 16 + h2) * DDIM
                               + (size_t)(l0 + ll) * FDIM] = cvt.v;
            }
        }
    }
}

// ---------------- kernel D: part[z] = x @ Wp^T — R14/R16 champion (frozen) ----------------
#define GBM 64
#define GBN 128
#define GBK 64
#define GSPLIT 16
#define GKSPL (DDIM / GSPLIT)    // 1024
#define GKST  (GKSPL / GBK)      // 16
#define LDA   72                 // A LDS stride: 144B ≡ 4 dwords mod 32 -> 2-way (free)
#define NWG   (16 * 3 * GSPLIT)  // 768 blocks, %8==0 (bijective XCD swizzle)

__launch_bounds__(256, 3)
__global__ void gemm2(const float* __restrict__ x, const unsigned short* __restrict__ Wp,
                      float* __restrict__ part) {
    __shared__ unsigned short As[2][GBM * LDA];   // 2 x 9.2 KB
    __shared__ unsigned short Bs[2][GBN * GBK];   // 2 x 16 KB, linear dest, swizzled content
    int bid = blockIdx.x;
    int swz = (bid & 7) * (NWG / 8) + (bid >> 3);
    int bz  = swz / 48;
    int rem = swz % 48;
    int by  = rem / 16;
    int bx  = rem % 16;
    int m0 = bx * GBM, n0 = by * GBN, k0 = bz * GKSPL;
    int tid = threadIdx.x, lane = tid & 63, wave = tid >> 6;
    int wm = wave >> 1, wn = wave & 1;

    int arow = tid >> 2, aseg = tid & 3;
    const float* ag = x + (size_t)(m0 + arow) * DDIM + k0 + aseg * 16;
    int brc  = lane >> 3;                       // row within 8-row chunk
    int bsg  = (lane & 7) ^ brc;                // T2 source-pre-swizzle

    f32x4 Ra[4], Rb[4];
    f32x4 acc[2][4] = {};

    auto aload = [&](f32x4* R, int s) {
        const float* a = ag + s * GBK;
        #pragma unroll
        for (int i = 0; i < 4; ++i) R[i] = *(const f32x4*)(a + 4 * i);
    };
    auto astore = [&](const f32x4* R, int buf) {
        unsigned int w[8];
        #pragma unroll
        for (int t = 0; t < 8; ++t) {
            float lo = R[t >> 1][(t & 1) * 2];
            float hi = R[t >> 1][(t & 1) * 2 + 1];
            asm("v_cvt_pk_bf16_f32 %0, %1, %2" : "=v"(w[t]) : "v"(lo), "v"(hi));
        }
        unsigned short* dst = &As[buf][arow * LDA + aseg * 16];
        u32x4 v0 = {w[0], w[1], w[2], w[3]};
        u32x4 v1 = {w[4], w[5], w[6], w[7]};
        *(u32x4*)dst       = v0;
        *(u32x4*)(dst + 8) = v1;
    };
    auto bstage = [&](int buf, int s) {
        #pragma unroll
        for (int q = 0; q < 4; ++q) {
            int c = wave * 4 + q;                  // 8-row chunk id (0..15)
            const unsigned short* g = Wp + (size_t)(n0 + c * 8 + brc) * DDIM
                                        + k0 + s * GBK + bsg * 8;
            __builtin_amdgcn_global_load_lds(
                (const __attribute__((address_space(1))) void*)g,
                (__attribute__((address_space(3))) void*)&Bs[buf][c * 512], 16, 0, 0);
        }
    };
    int frow = lane & 15, hi4 = lane >> 4;
    auto compute = [&](int buf) {
        #pragma unroll
        for (int ks = 0; ks < 2; ++ks) {
            bf16x8 av[2], bv[4];
            #pragma unroll
            for (int i = 0; i < 2; ++i)
                av[i] = *(const bf16x8*)&As[buf][(wm*32 + i*16 + frow) * LDA + ks*32 + hi4*8];
            #pragma unroll
            for (int j = 0; j < 4; ++j) {
                int rB = wn*64 + j*16 + frow;
                int sL = (ks*4 + hi4) ^ (frow & 7);    // un-swizzle on read
                bv[j] = *(const bf16x8*)&Bs[buf][rB * GBK + sL * 8];
            }
            #pragma unroll
            for (int i = 0; i < 2; ++i)
                #pragma unroll
                for (int j = 0; j < 4; ++j)
                    acc[i][j] = __builtin_amdgcn_mfma_f32_16x16x32_bf16(av[i], bv[j], acc[i][j], 0, 0, 0);
        }
    };

    // prologue: regs k0,k1; B0 DMA; A0 in LDS; barrier drains all
    aload(Ra, 0); aload(Rb, 1); bstage(0, 0); astore(Ra, 0);
    __syncthreads();

    for (int s2 = 0; s2 < GKST; s2 += 2) {
        {   int s = s2;                                  // even step, bufs 0
            if (s + 1 < GKST) bstage(1, s + 1);
            if (s + 2 < GKST) aload(Ra, s + 2);
            if (s + 1 < GKST) astore(Rb, 1);
            compute(0);
            __syncthreads();
        }
        {   int s = s2 + 1;                              // odd step, bufs 1
            if (s + 1 < GKST) bstage(0, s + 1);
            if (s + 2 < GKST) aload(Rb, s + 2);
            if (s + 1 < GKST) astore(Ra, 0);
            compute(1);
            __syncthreads();
        }
    }

    // epilogue: plain streaming stores to this k-split's private slab (no atomics)
    float* pslab = part + (size_t)bz * (BATCH * NH3);
    int orow = (lane >> 4) * 4, ocol = lane & 15;   // C/D: col=lane&15, row=(lane>>4)*4+r
    #pragma unroll
    for (int i = 0; i < 2; ++i)
        #pragma unroll
        for (int j = 0; j < 4; ++j)
            #pragma unroll
            for (int r = 0; r < 4; ++r)
                pslab[(size_t)(m0 + wm*32 + i*16 + orow + r) * NH3
                      + (n0 + wn*64 + j*16 + ocol)] = acc[i][j][r];
}

// ---------------- kernel E: fused MLP tail — 4 batch rows per block (frozen) ----------------
__launch_bounds__(1024, 2)
__global__ void mlp_fused2(const float* __restrict__ part, const float* __restrict__ be0,
                           const float* __restrict__ be1, const float* __restrict__ be2,
                           const float* __restrict__ Wf1, const float* __restrict__ bf1,
                           const float* __restrict__ Wf2, const float* __restrict__ bf2,
                           float* __restrict__ out) {
    __shared__ float fr[4][NH3];        // 6 KB
    __shared__ float hp[8][4][HDIM];    // 16 KB
    __shared__ float hs[4][HDIM];       // 2 KB
    int b0 = blockIdx.x * 4, tid = threadIdx.x;

    for (int e = tid; e < 4 * NH3; e += 1024) {       // slab-reduce 4 rows
        int rr = e / NH3, cc = e % NH3;
        float v = (cc < HDIM) ? be0[cc]
                : (cc < 2*HDIM ? be1[cc - HDIM] : be2[cc - 2*HDIM]);
        #pragma unroll
        for (int z = 0; z < GSPLIT; ++z)              // 16 independent loads
            v += part[(size_t)z * (BATCH * NH3) + (size_t)(b0 + rr) * NH3 + cc];
        fr[rr][cc] = v;
    }
    __syncthreads();

    int j = tid & 127, c = tid >> 7;                  // c = 0..7, 48 i's each
    int i0 = c * 48;
    float a0 = 0.f, a1 = 0.f, a2 = 0.f, a3 = 0.f;     // 4 independent chains of 48
    #pragma unroll
    for (int k = 0; k < 48; ++k) {
        float w = Wf1[(size_t)(i0 + k) * HDIM + j];   // ONE load, FOUR fmas
        float f0 = fr[0][i0 + k], f1 = fr[1][i0 + k];
        float f2 = fr[2][i0 + k], f3 = fr[3][i0 + k];
        a0 = fmaf(f0, w, a0);
        a1 = fmaf(f1, w, a1);
        a2 = fmaf(f2, w, a2);
        a3 = fmaf(f3, w, a3);
    }
    hp[c][0][j] = a0; hp[c][1][j] = a1; hp[c][2][j] = a2; hp[c][3][j] = a3;
    __syncthreads();

    if (tid < 4 * HDIM) {
        int rr = tid >> 7, jj = tid & 127;
        float v = bf1[jj];
        #pragma unroll
        for (int cc = 0; cc < 8; ++cc) v += hp[cc][rr][jj];
        hs[rr][jj] = fmaxf(v, 0.f);
    }
    __syncthreads();

    int lane = tid & 63, wave = tid >> 6;             // 16 waves
    int rr = wave & 3, base = wave >> 2;              // wave -> (row, class-stride-4 set)
    #pragma unroll
    for (int cc = base; cc < NCLS; cc += 4) {
        float pp = hs[rr][lane] * Wf2[(size_t)lane * NCLS + cc];
        pp = fmaf(hs[rr][lane + 64], Wf2[(size_t)(lane + 64) * NCLS + cc], pp);
        #pragma unroll
        for (int off = 32; off; off >>= 1) pp += __shfl_down(pp, off);
        if (lane == 0) out[(size_t)(b0 + rr) * NCLS + cc] = pp + bf2[cc];
    }
}

extern "C" void kernel_launch(void* const* d_in, const int* in_sizes, int n_in,
                              void* d_out, int out_size, void* d_ws, size_t ws_size,
                              hipStream_t stream) {
    const float* x   = (const float*)d_in[0];
    const float* We0 = (const float*)d_in[1];
    const float* be0 = (const float*)d_in[2];
    const float* We1 = (const float*)d_in[3];
    const float* be1 = (const float*)d_in[4];
    const float* We2 = (const float*)d_in[5];
    const float* be2 = (const float*)d_in[6];
    const float* Wf1 = (const float*)d_in[7];
    const float* bf1 = (const float*)d_in[8];
    const float* Wf2 = (const float*)d_in[9];
    const float* bf2 = (const float*)d_in[10];
    float* out = (float*)d_out;

    char* wsb = (char*)d_ws;
    size_t off = 0;
    unsigned short* Wp = (unsigned short*)(wsb + off); off += (size_t)NH3 * DDIM * sizeof(unsigned short);   // 12.6 MB
    float* u    = (float*)(wsb + off); off += (size_t)2 * PERIOD * FH * sizeof(float);                       // 0.39 MB
    float* u4   = (float*)(wsb + off); off += (size_t)PCHUNK * 2 * PERIOD * FH * sizeof(float);              // 1.57 MB
    float* t1   = (float*)(wsb + off); off += (size_t)NSLOT * FH * sizeof(float);                            // 0.39 MB
    float* t2   = (float*)(wsb + off); off += (size_t)NSLOT * FH * sizeof(float);                            // 0.39 MB
    float* part = (float*)(wsb + off); off += (size_t)GSPLIT * BATCH * NH3 * sizeof(float);                  // 25.2 MB

    phase_sums_part<<<(2 * PERIOD * (FH / 4) * PCHUNK + 255) / 256, 256, 0, stream>>>(We1, We2, u4);
    phase_reduce<<<(2 * PERIOD * (FH / 4) + 255) / 256, 256, 0, stream>>>(u4, u);
    build_tables<<<(NSLOT * (FH / 4) + 255) / 256, 256, 0, stream>>>(u, t1, t2);
    build_wp<<<dim3(8, L_LEN / NLB), 256, 0, stream>>>(We0, We2, t1, t2, Wp);
    gemm2<<<NWG, 256, 0, stream>>>(x, Wp, part);
    mlp_fused2<<<BATCH / 4, 1024, 0, stream>>>(part, be0, be1, be2, Wf1, bf1, Wf2, bf2, out);
}

// Round 18
// 65.835 us; speedup vs baseline: 1.8320x; 1.0260x over previous
//
#include <hip/hip_runtime.h>

#define L_LEN  1024
#define FDIM   16
#define PERIOD 24
#define HDIM   128
#define BATCH  1024
#define DDIM   (L_LEN*FDIM)      // 16384
#define NH3    (3*HDIM)          // 384
#define THALF  12
#define NCLS   10
#define FH     (FDIM*HDIM)       // 2048
#define NLB    8                 // l-strip per build_wp block
#define PCHUNK 4                 // phase_sums l-chunks
#define NSLOT  48                // 24 interior phases + 24 edge l's

typedef short bf16x8  __attribute__((ext_vector_type(8)));
typedef short bf16x16 __attribute__((ext_vector_type(16)));
typedef float f32x4   __attribute__((ext_vector_type(4)));
typedef unsigned int u32x4 __attribute__((ext_vector_type(4)));

__device__ __forceinline__ unsigned short f2bf(float f) {
    unsigned int u = __float_as_uint(f);
    u += 0x7FFFu + ((u >> 16) & 1u);           // RNE
    return (unsigned short)(u >> 16);
}
__device__ __forceinline__ float cinv(int p) { return (p < 16) ? (1.0f/43.0f) : (1.0f/42.0f); }

// ---------------- kernel B1: partial per-phase column sums (4 l-chunks, 384 blocks) ----------------
__global__ void phase_sums_part(const float* __restrict__ We1, const float* __restrict__ We2,
                                float* __restrict__ u4) {
    int idx = blockIdx.x * blockDim.x + threadIdx.x;
    if (idx >= 2 * PERIOD * (FH / 4) * PCHUNK) return;
    int c    = idx / (2 * PERIOD * (FH / 4));
    int rem  = idx % (2 * PERIOD * (FH / 4));
    int w    = rem / (PERIOD * (FH / 4));
    int rem2 = rem % (PERIOD * (FH / 4));
    int p    = rem2 / (FH / 4);
    int fh4  = rem2 % (FH / 4);
    const float* W = w ? We2 : We1;
    int lbeg = c * (L_LEN / PCHUNK);
    int lend = lbeg + (L_LEN / PCHUNK);
    int l0   = lbeg + ((p - lbeg) % PERIOD + PERIOD) % PERIOD;
    f32x4 s = {0.f, 0.f, 0.f, 0.f};
    for (int l = l0; l < lend; l += PERIOD)
        s += *(const f32x4*)&W[(size_t)l * FH + fh4 * 4];
    *(f32x4*)&u4[(size_t)c * (2 * PERIOD * FH) + (size_t)w * PERIOD * FH + p * FH + fh4 * 4] = s;
}

// ---------------- kernel B2: u = sum of 4 partials ----------------
__global__ void phase_reduce(const float* __restrict__ u4, float* __restrict__ u) {
    int idx = blockIdx.x * blockDim.x + threadIdx.x;
    if (idx >= 2 * PERIOD * (FH / 4)) return;
    size_t o = (size_t)idx * 4;
    f32x4 s = *(const f32x4*)&u4[o];
    #pragma unroll
    for (int c = 1; c < PCHUNK; ++c)
        s += *(const f32x4*)&u4[(size_t)c * (2 * PERIOD * FH) + o];
    *(f32x4*)&u[o] = s;
}

// ---------------- kernel B3: u-part tables, periodic in l ----------------
__global__ void build_tables(const float* __restrict__ u, float* __restrict__ t1,
                             float* __restrict__ t2) {
    int idx = blockIdx.x * blockDim.x + threadIdx.x;   // 48 * 512
    if (idx >= NSLOT * (FH / 4)) return;
    int s   = idx / (FH / 4);
    int fh4 = idx % (FH / 4);
    const float* u1 = u + (size_t)fh4 * 4;
    const float* u2 = u + (size_t)PERIOD * FH + (size_t)fh4 * 4;
    const float inv25 = 1.0f / 25.0f;
    f32x4 v1, v2;
    f32x4 mav1 = {0.f, 0.f, 0.f, 0.f}, mav2 = {0.f, 0.f, 0.f, 0.f};

    if (s < PERIOD) {                                  // interior phase
        int p  = s;
        int pr = (p + THALF) % PERIOD;
        f32x4 Sv1 = {0.f, 0.f, 0.f, 0.f}, Sv2 = {0.f, 0.f, 0.f, 0.f};
        #pragma unroll
        for (int q = 0; q < PERIOD; ++q) {
            float cq = cinv(q);
            Sv1 += *(const f32x4*)&u1[(size_t)q * FH] * cq;
            Sv2 += *(const f32x4*)&u2[(size_t)q * FH] * cq;
        }
        v1 = *(const f32x4*)&u1[(size_t)p * FH] * cinv(p);
        v2 = *(const f32x4*)&u2[(size_t)p * FH] * cinv(p);
        mav1 = (Sv1 + *(const f32x4*)&u1[(size_t)pr * FH] * cinv(pr)) * inv25;
        mav2 = (Sv2 + *(const f32x4*)&u2[(size_t)pr * FH] * cinv(pr)) * inv25;
    } else {                                           // edge l, exact clipped window
        int e = s - PERIOD;
        int l = (e < THALF) ? e : (L_LEN - THALF + (e - THALF));
        int pl = l % PERIOD;
        v1 = *(const f32x4*)&u1[(size_t)pl * FH] * cinv(pl);
        v2 = *(const f32x4*)&u2[(size_t)pl * FH] * cinv(pl);
        #pragma unroll
        for (int dl = -THALF; dl <= THALF; ++dl) {
            int j = l + dl;
            if (j >= 0 && j < L_LEN) {
                int p = j % PERIOD;
                float ci = cinv(p);
                mav1 += *(const f32x4*)&u1[(size_t)p * FH] * ci;
                mav2 += *(const f32x4*)&u2[(size_t)p * FH] * ci;
            }
        }
        mav1 *= inv25; mav2 *= inv25;
    }
    *(f32x4*)&t1[(size_t)s * FH + fh4 * 4] = v1 - mav1;   // out1 = t1
    *(f32x4*)&t2[(size_t)s * FH + fh4 * 4] = mav2 - v2;   // out2 = w2 - s2/25 + t2
}

// ---------------- kernel C: build W' (bf16) — window regs + table lookups ----------------
__launch_bounds__(256, 3)
__global__ void build_wp(const float* __restrict__ We0, const float* __restrict__ We2,
                         const float* __restrict__ t1, const float* __restrict__ t2,
                         unsigned short* __restrict__ Wp) {
    __shared__ unsigned short tile[3][NLB][16][18];   // 13.8 KB
    int f  = threadIdx.x >> 4;
    int hl = threadIdx.x & 15;
    int h  = blockIdx.x * 16 + hl;
    int l0 = blockIdx.y * NLB;
    int fh = f * HDIM + h;

    float w0[NLB + 25], w2[NLB + 25];
    #pragma unroll
    for (int i = 0; i < NLB + 25; ++i) {
        int j = l0 - THALF + i;
        if (j >= 0 && j < L_LEN) {
            w0[i] = We0[(size_t)j * FH + fh];
            w2[i] = We2[(size_t)j * FH + fh];
        } else { w0[i] = 0.f; w2[i] = 0.f; }
    }

    float s0 = 0.f, s2 = 0.f;
    #pragma unroll
    for (int i = 0; i < 25; ++i) { s0 += w0[i]; s2 += w2[i]; }

    const float inv25 = 1.0f / 25.0f;
    #pragma unroll
    for (int r = 0; r < NLB; ++r) {
        int l = l0 + r;
        int slot = (l >= THALF && l < L_LEN - THALF)
                 ? (l % PERIOD)
                 : (PERIOD + ((l < THALF) ? l : (THALF + (l - (L_LEN - THALF)))));
        float tt1 = t1[(size_t)slot * FH + fh];
        float tt2 = t2[(size_t)slot * FH + fh];

        float out0 = s0 * inv25;                        // (T We0)[l]
        float out1 = tt1;                               // S^T We1
        float out2 = w2[r + THALF] - s2 * inv25 + tt2;  // (I-T-S)^T We2

        tile[0][r][hl][f] = f2bf(out0);
        tile[1][r][hl][f] = f2bf(out1);
        tile[2][r][hl][f] = f2bf(out2);

        s0 += w0[r + 25] - w0[r];                       // register-only slide
        s2 += w2[r + 25] - w2[r];
    }
    __syncthreads();

    {
        int cid = threadIdx.x;
        #pragma unroll
        for (int pass = 0; pass < 2; ++pass, cid += 256) {
            if (cid < 3 * 16 * NLB) {
                int m  = cid / (16 * NLB);
                int rm = cid % (16 * NLB);
                int h2 = rm / NLB;
                int ll = rm % NLB;
                const unsigned int* src = (const unsigned int*)&tile[m][ll][h2][0];
                union { unsigned int d[8]; bf16x16 v; } cvt;
                #pragma unroll
                for (int i = 0; i < 8; ++i) cvt.d[i] = src[i];
                *(bf16x16*)&Wp[(size_t)(m * HDIM + blockIdx.x * 16 + h2) * DDIM
                               + (size_t)(l0 + ll) * FDIM] = cvt.v;
            }
        }
    }
}

// ---------------- kernel D: part[z] = x @ Wp^T — BN=192 variant (2 n-blocks, 24 MFMA/step) ----------------
#define GBM 64
#define GBN 192
#define GBK 64
#define GSPLIT 16
#define GKSPL (DDIM / GSPLIT)    // 1024
#define GKST  (GKSPL / GBK)      // 16
#define LDA   72                 // A LDS stride: 144B ≡ 4 dwords mod 32 -> 2-way (free)
#define NWG2  (16 * 2 * GSPLIT)  // 512 blocks, %8==0 (bijective XCD swizzle)

__launch_bounds__(256, 2)
__global__ void gemm3(const float* __restrict__ x, const unsigned short* __restrict__ Wp,
                      float* __restrict__ part) {
    __shared__ unsigned short As[2][GBM * LDA];   // 2 x 9.2 KB
    __shared__ unsigned short Bs[2][GBN * GBK];   // 2 x 24 KB, linear dest, swizzled content
    int bid = blockIdx.x;
    int swz = (bid & 7) * (NWG2 / 8) + (bid >> 3);
    int bz  = swz / 32;            // 0..15
    int rem = swz % 32;
    int by  = rem / 16;            // 0..1
    int bx  = rem % 16;            // 0..15
    int m0 = bx * GBM, n0 = by * GBN, k0 = bz * GKSPL;
    int tid = threadIdx.x, lane = tid & 63, wave = tid >> 6;
    int wn = wave;                 // 4 waves: 1m x 4n, wave tile 64 x 48

    int arow = tid >> 2, aseg = tid & 3;
    const float* ag = x + (size_t)(m0 + arow) * DDIM + k0 + aseg * 16;
    int brc  = lane >> 3;                       // row within 8-row chunk
    int bsg  = (lane & 7) ^ brc;                // T2 source-pre-swizzle

    f32x4 Ra[4], Rb[4];
    f32x4 acc[4][3] = {};

    auto aload = [&](f32x4* R, int s) {
        const float* a = ag + s * GBK;
        #pragma unroll
        for (int i = 0; i < 4; ++i) R[i] = *(const f32x4*)(a + 4 * i);
    };
    auto astore = [&](const f32x4* R, int buf) {
        unsigned int w[8];
        #pragma unroll
        for (int t = 0; t < 8; ++t) {
            float lo = R[t >> 1][(t & 1) * 2];
            float hi = R[t >> 1][(t & 1) * 2 + 1];
            asm("v_cvt_pk_bf16_f32 %0, %1, %2" : "=v"(w[t]) : "v"(lo), "v"(hi));
        }
        unsigned short* dst = &As[buf][arow * LDA + aseg * 16];
        u32x4 v0 = {w[0], w[1], w[2], w[3]};
        u32x4 v1 = {w[4], w[5], w[6], w[7]};
        *(u32x4*)dst       = v0;
        *(u32x4*)(dst + 8) = v1;
    };
    auto bstage = [&](int buf, int s) {
        #pragma unroll
        for (int q = 0; q < 6; ++q) {
            int c = wave * 6 + q;                  // 8-row chunk id (0..23) -> 192 rows
            const unsigned short* g = Wp + (size_t)(n0 + c * 8 + brc) * DDIM
                                        + k0 + s * GBK + bsg * 8;
            __builtin_amdgcn_global_load_lds(
                (const __attribute__((address_space(1))) void*)g,
                (__attribute__((address_space(3))) void*)&Bs[buf][c * 512], 16, 0, 0);
        }
    };
    int frow = lane & 15, hi4 = lane >> 4;
    auto compute = [&](int buf) {
        #pragma unroll
        for (int ks = 0; ks < 2; ++ks) {
            bf16x8 av[4], bv[3];
            #pragma unroll
            for (int i = 0; i < 4; ++i)
                av[i] = *(const bf16x8*)&As[buf][(i*16 + frow) * LDA + ks*32 + hi4*8];
            #pragma unroll
            for (int j = 0; j < 3; ++j) {
                int rB = wn*48 + j*16 + frow;
                int sL = (ks*4 + hi4) ^ (frow & 7);    // un-swizzle on read
                bv[j] = *(const bf16x8*)&Bs[buf][rB * GBK + sL * 8];
            }
            #pragma unroll
            for (int i = 0; i < 4; ++i)
                #pragma unroll
                for (int j = 0; j < 3; ++j)
                    acc[i][j] = __builtin_amdgcn_mfma_f32_16x16x32_bf16(av[i], bv[j], acc[i][j], 0, 0, 0);
        }
    };

    // prologue: regs k0,k1; B0 DMA; A0 in LDS; barrier drains all
    aload(Ra, 0); aload(Rb, 1); bstage(0, 0); astore(Ra, 0);
    __syncthreads();

    for (int s2 = 0; s2 < GKST; s2 += 2) {
        {   int s = s2;                                  // even step, bufs 0
            if (s + 1 < GKST) bstage(1, s + 1);
            if (s + 2 < GKST) aload(Ra, s + 2);
            if (s + 1 < GKST) astore(Rb, 1);
            compute(0);
            __syncthreads();
        }
        {   int s = s2 + 1;                              // odd step, bufs 1
            if (s + 1 < GKST) bstage(0, s + 1);
            if (s + 2 < GKST) aload(Rb, s + 2);
            if (s + 1 < GKST) astore(Ra, 0);
            compute(1);
            __syncthreads();
        }
    }

    // epilogue: plain streaming stores to this k-split's private slab (no atomics)
    float* pslab = part + (size_t)bz * (BATCH * NH3);
    int orow = (lane >> 4) * 4, ocol = lane & 15;   // C/D: col=lane&15, row=(lane>>4)*4+r
    #pragma unroll
    for (int i = 0; i < 4; ++i)
        #pragma unroll
        for (int j = 0; j < 3; ++j)
            #pragma unroll
            for (int r = 0; r < 4; ++r)
                pslab[(size_t)(m0 + i*16 + orow + r) * NH3
                      + (n0 + wn*48 + j*16 + ocol)] = acc[i][j][r];
}

// ---------------- kernel E: fused MLP tail — 4 batch rows per block (frozen) ----------------
__launch_bounds__(1024, 2)
__global__ void mlp_fused2(const float* __restrict__ part, const float* __restrict__ be0,
                           const float* __restrict__ be1, const float* __restrict__ be2,
                           const float* __restrict__ Wf1, const float* __restrict__ bf1,
                           const float* __restrict__ Wf2, const float* __restrict__ bf2,
                           float* __restrict__ out) {
    __shared__ float fr[4][NH3];        // 6 KB
    __shared__ float hp[8][4][HDIM];    // 16 KB
    __shared__ float hs[4][HDIM];       // 2 KB
    int b0 = blockIdx.x * 4, tid = threadIdx.x;

    for (int e = tid; e < 4 * NH3; e += 1024) {       // slab-reduce 4 rows
        int rr = e / NH3, cc = e % NH3;
        float v = (cc < HDIM) ? be0[cc]
                : (cc < 2*HDIM ? be1[cc - HDIM] : be2[cc - 2*HDIM]);
        #pragma unroll
        for (int z = 0; z < GSPLIT; ++z)              // 16 independent loads
            v += part[(size_t)z * (BATCH * NH3) + (size_t)(b0 + rr) * NH3 + cc];
        fr[rr][cc] = v;
    }
    __syncthreads();

    int j = tid & 127, c = tid >> 7;                  // c = 0..7, 48 i's each
    int i0 = c * 48;
    float a0 = 0.f, a1 = 0.f, a2 = 0.f, a3 = 0.f;     // 4 independent chains of 48
    #pragma unroll
    for (int k = 0; k < 48; ++k) {
        float w = Wf1[(size_t)(i0 + k) * HDIM + j];   // ONE load, FOUR fmas
        float f0 = fr[0][i0 + k], f1 = fr[1][i0 + k];
        float f2 = fr[2][i0 + k], f3 = fr[3][i0 + k];
        a0 = fmaf(f0, w, a0);
        a1 = fmaf(f1, w, a1);
        a2 = fmaf(f2, w, a2);
        a3 = fmaf(f3, w, a3);
    }
    hp[c][0][j] = a0; hp[c][1][j] = a1; hp[c][2][j] = a2; hp[c][3][j] = a3;
    __syncthreads();

    if (tid < 4 * HDIM) {
        int rr = tid >> 7, jj = tid & 127;
        float v = bf1[jj];
        #pragma unroll
        for (int cc = 0; cc < 8; ++cc) v += hp[cc][rr][jj];
        hs[rr][jj] = fmaxf(v, 0.f);
    }
    __syncthreads();

    int lane = tid & 63, wave = tid >> 6;             // 16 waves
    int rr = wave & 3, base = wave >> 2;              // wave -> (row, class-stride-4 set)
    #pragma unroll
    for (int cc = base; cc < NCLS; cc += 4) {
        float pp = hs[rr][lane] * Wf2[(size_t)lane * NCLS + cc];
        pp = fmaf(hs[rr][lane + 64], Wf2[(size_t)(lane + 64) * NCLS + cc], pp);
        #pragma unroll
        for (int off = 32; off; off >>= 1) pp += __shfl_down(pp, off);
        if (lane == 0) out[(size_t)(b0 + rr) * NCLS + cc] = pp + bf2[cc];
    }
}

extern "C" void kernel_launch(void* const* d_in, const int* in_sizes, int n_in,
                              void* d_out, int out_size, void* d_ws, size_t ws_size,
                              hipStream_t stream) {
    const float* x   = (const float*)d_in[0];
    const float* We0 = (const float*)d_in[1];
    const float* be0 = (const float*)d_in[2];
    const float* We1 = (const float*)d_in[3];
    const float* be1 = (const float*)d_in[4];
    const float* We2 = (const float*)d_in[5];
    const float* be2 = (const float*)d_in[6];
    const float* Wf1 = (const float*)d_in[7];
    const float* bf1 = (const float*)d_in[8];
    const float* Wf2 = (const float*)d_in[9];
    const float* bf2 = (const float*)d_in[10];
    float* out = (float*)d_out;

    char* wsb = (char*)d_ws;
    size_t off = 0;
    unsigned short* Wp = (unsigned short*)(wsb + off); off += (size_t)NH3 * DDIM * sizeof(unsigned short);   // 12.6 MB
    float* u    = (float*)(wsb + off); off += (size_t)2 * PERIOD * FH * sizeof(float);                       // 0.39 MB
    float* u4   = (float*)(wsb + off); off += (size_t)PCHUNK * 2 * PERIOD * FH * sizeof(float);              // 1.57 MB
    float* t1   = (float*)(wsb + off); off += (size_t)NSLOT * FH * sizeof(float);                            // 0.39 MB
    float* t2   = (float*)(wsb + off); off += (size_t)NSLOT * FH * sizeof(float);                            // 0.39 MB
    float* part = (float*)(wsb + off); off += (size_t)GSPLIT * BATCH * NH3 * sizeof(float);                  // 25.2 MB

    phase_sums_part<<<(2 * PERIOD * (FH / 4) * PCHUNK + 255) / 256, 256, 0, stream>>>(We1, We2, u4);
    phase_reduce<<<(2 * PERIOD * (FH / 4) + 255) / 256, 256, 0, stream>>>(u4, u);
    build_tables<<<(NSLOT * (FH / 4) + 255) / 256, 256, 0, stream>>>(u, t1, t2);
    build_wp<<<dim3(8, L_LEN / NLB), 256, 0, stream>>>(We0, We2, t1, t2, Wp);
    gemm3<<<NWG2, 256, 0, stream>>>(x, Wp, part);
    mlp_fused2<<<BATCH / 4, 1024, 0, stream>>>(part, be0, be1, be2, Wf1, bf1, Wf2, bf2, out);
}